// Round 1
// baseline (142.758 us; speedup 1.0000x reference)
//
#include <hip/hip_runtime.h>

#define GATE_SCALE 1.7015f

typedef __attribute__((ext_vector_type(8))) short short8;
typedef __attribute__((ext_vector_type(4))) float f32x4;

__device__ __forceinline__ ushort f2bf(float f) {
    union { float f; unsigned u; } v; v.f = f;
    unsigned u = v.u;
    unsigned r = (u + 0x7FFFu + ((u >> 16) & 1u)) >> 16;
    return (ushort)r;
}

__device__ __forceinline__ void gl2lds16(const void* g, void* l) {
    __builtin_amdgcn_global_load_lds((const __attribute__((address_space(1))) void*)g,
                                     (__attribute__((address_space(3))) void*)l, 16, 0, 0);
}

// ---------------------------------------------------------------------------
// Kernel 1: convert x_cat (concat of x_real,x_imag rows) and W_gate to bf16
// xc: [2048][2048] bf16, wb: [1024][2048] bf16
// ---------------------------------------------------------------------------
__global__ void convert_kernel(const float* __restrict__ xr, const float* __restrict__ xi,
                               const float* __restrict__ W,
                               ushort* __restrict__ xc, ushort* __restrict__ wb) {
    const int XCV = 2048 * 2048 / 4;   // float4 count for xc
    const int WV  = 1024 * 2048 / 4;   // float4 count for W
    int stride = gridDim.x * blockDim.x;
    for (int v = blockIdx.x * blockDim.x + threadIdx.x; v < XCV + WV; v += stride) {
        float4 f;
        ushort* dst;
        if (v < XCV) {
            int idx = v * 4;
            int m = idx >> 11;
            int k = idx & 2047;
            const float* s = (k < 1024) ? (xr + m * 1024 + k) : (xi + m * 1024 + k - 1024);
            f = *(const float4*)s;
            dst = xc + idx;
        } else {
            int idx = (v - XCV) * 4;
            f = *(const float4*)(W + idx);
            dst = wb + idx;
        }
        ushort4 o;
        o.x = f2bf(f.x); o.y = f2bf(f.y); o.z = f2bf(f.z); o.w = f2bf(f.w);
        *(ushort4*)dst = o;
    }
}

// ---------------------------------------------------------------------------
// Kernel 2: per-n complex powers  P[n][k][o*8+i][2] = (A^(k+1)) for k=0..3
// A = 0.5(Ar - Ar^T) + i*0.5(Ai + Ai^T)
// ---------------------------------------------------------------------------
__global__ void powers_kernel(const float* __restrict__ Ar, const float* __restrict__ Ai,
                              float* __restrict__ P) {
    int n = blockIdx.x;
    int t = threadIdx.x;           // 0..63
    int o = t >> 3, i = t & 7;
    __shared__ float Are[64], Aim[64];
    __shared__ float Cre[64], Cim[64];
    const float* arn = Ar + n * 64;
    const float* ain = Ai + n * 64;
    float a_r = 0.5f * (arn[o * 8 + i] - arn[i * 8 + o]);
    float a_i = 0.5f * (ain[o * 8 + i] + ain[i * 8 + o]);
    Are[t] = a_r; Aim[t] = a_i;
    float cr = a_r, ci = a_i;
    float* Pn = P + n * 512;
    Pn[t * 2] = cr; Pn[t * 2 + 1] = ci;
    __syncthreads();
    for (int k = 1; k < 4; ++k) {
        Cre[t] = cr; Cim[t] = ci;
        __syncthreads();
        float nr = 0.f, nim = 0.f;
        #pragma unroll
        for (int q = 0; q < 8; ++q) {
            float pr = Cre[o * 8 + q], pi = Cim[o * 8 + q];
            float br = Are[q * 8 + i], bi = Aim[q * 8 + i];
            nr  += pr * br - pi * bi;
            nim += pr * bi + pi * br;
        }
        cr = nr; ci = nim;
        Pn[k * 128 + t * 2] = cr; Pn[k * 128 + t * 2 + 1] = ci;
        __syncthreads();
    }
}

// ---------------------------------------------------------------------------
// Kernel 3: GEMM gate = sigmoid((xc @ W^T + b)*1.7015), then 8-col block mean
// BM=128, BN=64, BK=64; 256 threads = 4 waves (2x2); outputs g[2048][128]
// ---------------------------------------------------------------------------
__launch_bounds__(256)
__global__ void gemm_gate_kernel(const ushort* __restrict__ A,   // xc [2048][2048]
                                 const ushort* __restrict__ Bw,  // wb [1024][2048]
                                 const float* __restrict__ bias, // [1024]
                                 float* __restrict__ g) {        // [2048][128]
    __shared__ __align__(16) ushort lA[128 * 64];
    __shared__ __align__(16) ushort lB[64 * 64];
    int tid = threadIdx.x;
    int lane = tid & 63;
    int wid = tid >> 6;
    int bm = blockIdx.x, bn = blockIdx.y;
    int m0 = bm * 128, n0 = bn * 64;
    int wm = wid >> 1, wn = wid & 1;

    f32x4 acc[4][2] = {};

    int lrow = lane & 15;
    int kgrp = (lane >> 4) * 8;

    for (int k0 = 0; k0 < 2048; k0 += 64) {
        __syncthreads();
        #pragma unroll
        for (int q = 0; q < 4; ++q) {
            int c = q * 256 + tid;
            int row = c >> 3, c8 = c & 7;
            gl2lds16(&A[(m0 + row) * 2048 + k0 + c8 * 8], &lA[c * 8]);
        }
        #pragma unroll
        for (int q = 0; q < 2; ++q) {
            int c = q * 256 + tid;
            int row = c >> 3, c8 = c & 7;
            gl2lds16(&Bw[(n0 + row) * 2048 + k0 + c8 * 8], &lB[c * 8]);
        }
        __syncthreads();
        #pragma unroll
        for (int ks = 0; ks < 2; ++ks) {
            short8 af[4], bf[2];
            #pragma unroll
            for (int mi = 0; mi < 4; ++mi)
                af[mi] = *(const short8*)&lA[(wm * 64 + mi * 16 + lrow) * 64 + ks * 32 + kgrp];
            #pragma unroll
            for (int ni = 0; ni < 2; ++ni)
                bf[ni] = *(const short8*)&lB[(wn * 32 + ni * 16 + lrow) * 64 + ks * 32 + kgrp];
            #pragma unroll
            for (int mi = 0; mi < 4; ++mi)
                #pragma unroll
                for (int ni = 0; ni < 2; ++ni)
                    acc[mi][ni] = __builtin_amdgcn_mfma_f32_16x16x32_bf16(af[mi], bf[ni], acc[mi][ni], 0, 0, 0);
        }
    }

    // epilogue: sigmoid + mean over 8-col groups
    int rowg = (lane >> 4) * 4;
    #pragma unroll
    for (int mi = 0; mi < 4; ++mi) {
        #pragma unroll
        for (int ni = 0; ni < 2; ++ni) {
            int dcol = n0 + wn * 32 + ni * 16 + lrow;
            float bv = bias[dcol];
            #pragma unroll
            for (int r = 0; r < 4; ++r) {
                int mrow = m0 + wm * 64 + mi * 16 + rowg + r;
                float z = (acc[mi][ni][r] + bv) * GATE_SCALE;
                float gate = 1.0f / (1.0f + __expf(-z));
                gate += __shfl_xor(gate, 1);
                gate += __shfl_xor(gate, 2);
                gate += __shfl_xor(gate, 4);
                if ((lane & 7) == 0)
                    g[mrow * 128 + (dcol >> 3)] = gate * 0.125f;
            }
        }
    }
}

// ---------------------------------------------------------------------------
// Kernel 4: apply  out = x + sum_{k=1..4} 2(-g)^k A^k x   (complex, per site)
// block: 256 threads = 32 n-lanes x 8 m; grid (4 n-chunks, 64 m-chunks)
// ---------------------------------------------------------------------------
__launch_bounds__(256)
__global__ void apply_kernel(const float* __restrict__ xr, const float* __restrict__ xi,
                             const float* __restrict__ g,   // [2048][128]
                             const float* __restrict__ P,   // [128][4][64][2]
                             float* __restrict__ outr, float* __restrict__ outi) {
    __shared__ float lp[32 * 512];   // exactly 64 KB, XOR-swizzled
    int tid = threadIdx.x;
    int n0 = blockIdx.x * 32;
    int m0 = blockIdx.y * 32;

    // stage 32 n * 512 floats, swizzled: e' = e ^ ((n&15)<<1)
    for (int v = tid; v < 16384; v += 256) {
        int n = v >> 9;
        int e = v & 511;
        lp[n * 512 + (e ^ ((n & 15) << 1))] = P[(n0 + n) * 512 + e];
    }
    __syncthreads();

    int nl = tid & 31;
    int ml = tid >> 5;   // 0..7
    const float* pn = &lp[nl * 512];
    int xsw = (nl & 15) << 1;
    int dbase = (n0 + nl) * 8;

    for (int it = 0; it < 4; ++it) {
        int m = m0 + it * 8 + ml;
        const float4* xr4 = (const float4*)&xr[m * 1024 + dbase];
        const float4* xi4 = (const float4*)&xi[m * 1024 + dbase];
        float4 a = xr4[0], b = xr4[1];
        float4 c = xi4[0], d = xi4[1];
        float vr[8] = {a.x, a.y, a.z, a.w, b.x, b.y, b.z, b.w};
        float vi[8] = {c.x, c.y, c.z, c.w, d.x, d.y, d.z, d.w};
        float gv = g[m * 128 + n0 + nl];
        float g2 = gv * gv;
        float cs[4] = {-2.f * gv, 2.f * g2, -2.f * g2 * gv, 2.f * g2 * g2};
        float orr[8], oii[8];
        #pragma unroll
        for (int o = 0; o < 8; ++o) { orr[o] = vr[o]; oii[o] = vi[o]; }
        #pragma unroll
        for (int k = 0; k < 4; ++k) {
            #pragma unroll
            for (int o = 0; o < 8; ++o) {
                float ar = 0.f, ai = 0.f;
                #pragma unroll
                for (int q = 0; q < 8; ++q) {
                    int e = (k * 64 + o * 8 + q) * 2;
                    float pr = pn[(e ^ xsw)];
                    float pi = pn[(e ^ xsw) + 1];
                    ar += pr * vr[q] - pi * vi[q];
                    ai += pr * vi[q] + pi * vr[q];
                }
                orr[o] += cs[k] * ar;
                oii[o] += cs[k] * ai;
            }
        }
        float4 o0 = {orr[0], orr[1], orr[2], orr[3]};
        float4 o1 = {orr[4], orr[5], orr[6], orr[7]};
        float4 o2 = {oii[0], oii[1], oii[2], oii[3]};
        float4 o3 = {oii[4], oii[5], oii[6], oii[7]};
        *(float4*)&outr[m * 1024 + dbase]     = o0;
        *(float4*)&outr[m * 1024 + dbase + 4] = o1;
        *(float4*)&outi[m * 1024 + dbase]     = o2;
        *(float4*)&outi[m * 1024 + dbase + 4] = o3;
    }
}

// ---------------------------------------------------------------------------
extern "C" void kernel_launch(void* const* d_in, const int* in_sizes, int n_in,
                              void* d_out, int out_size, void* d_ws, size_t ws_size,
                              hipStream_t stream) {
    const float* xr = (const float*)d_in[0];
    const float* xi = (const float*)d_in[1];
    const float* Ar = (const float*)d_in[2];
    const float* Ai = (const float*)d_in[3];
    const float* W  = (const float*)d_in[4];
    const float* bg = (const float*)d_in[5];
    float* out = (float*)d_out;

    char* ws = (char*)d_ws;
    ushort* xc = (ushort*)(ws);                  // 2048*2048*2 = 8388608 B
    ushort* wb = (ushort*)(ws + 8388608);        // 1024*2048*2 = 4194304 B
    float*  g  = (float*) (ws + 12582912);       // 2048*128*4  = 1048576 B
    float*  P  = (float*) (ws + 13631488);       // 128*512*4   = 262144 B

    hipLaunchKernelGGL(convert_kernel, dim3(1024), dim3(256), 0, stream, xr, xi, W, xc, wb);
    hipLaunchKernelGGL(powers_kernel, dim3(128), dim3(64), 0, stream, Ar, Ai, P);
    hipLaunchKernelGGL(gemm_gate_kernel, dim3(16, 16), dim3(256), 0, stream, xc, wb, bg, g);
    hipLaunchKernelGGL(apply_kernel, dim3(4, 64), dim3(256), 0, stream,
                       xr, xi, g, P, out, out + 2 * 1024 * 1024);
}